// Round 1
// baseline (2070.109 us; speedup 1.0000x reference)
//
#include <hip/hip_runtime.h>
#include <cstdint>

// Problem constants (fixed by setup_inputs):
//   input [32,64,64,256] fp32 -> N=131072 rows x DIM=256
//   embed [256,2048] fp32     -> DIM=256 x NE=2048
// d_out layout (fp32): quantize[33554432] | diff[1] | embed_ind_as_float[131072]
// ws layout (fp32):    embT[524288] | enorm[2048] | partials[32768]

#define NROWS   131072
#define DIM     256
#define NE      2048
#define TM      64          // rows per block in argmin kernel
#define NBLK_B  (NROWS / TM)   // 2048
#define GATHER_ROWS_PER_BLOCK 4
#define NBLK_C  (NROWS / GATHER_ROWS_PER_BLOCK) // 32768

// ---------------------------------------------------------------------------
// Kernel A1: enorm[j] = sum_d embed[d][j]^2
// ---------------------------------------------------------------------------
__global__ __launch_bounds__(256) void enorm_kernel(
    const float* __restrict__ embed, float* __restrict__ enorm) {
  const int j = blockIdx.x * 256 + threadIdx.x;
  float s = 0.f;
#pragma unroll 8
  for (int d = 0; d < DIM; ++d) {
    const float v = embed[(size_t)d * NE + j];
    s = fmaf(v, v, s);
  }
  enorm[j] = s;
}

// ---------------------------------------------------------------------------
// Kernel A2: embT[j][d] = embed[d][j]   (tiled 32x32 transpose)
// ---------------------------------------------------------------------------
__global__ __launch_bounds__(256) void transpose_kernel(
    const float* __restrict__ embed, float* __restrict__ embT) {
  __shared__ float tile[32][33];
  const int tx = threadIdx.x;  // 0..31
  const int ty = threadIdx.y;  // 0..7
  const int j0 = blockIdx.x * 32;
  const int d0 = blockIdx.y * 32;
#pragma unroll
  for (int i = 0; i < 4; ++i) {
    const int dd = ty + i * 8;
    tile[dd][tx] = embed[(size_t)(d0 + dd) * NE + j0 + tx];
  }
  __syncthreads();
#pragma unroll
  for (int i = 0; i < 4; ++i) {
    const int jj = ty + i * 8;
    embT[(size_t)(j0 + jj) * DIM + d0 + tx] = tile[tx][jj];
  }
}

// ---------------------------------------------------------------------------
// Kernel B: fused scores GEMM + argmin.
// Block = 256 threads (4 waves), TM=64 rows/block, grid = 2048 blocks.
// A-tile (64 rows x 256 k) staged k-major in 64 KB LDS, read once from HBM.
// Wave w handles its own 64-code strip per ct iteration (codes ct*256 + w*64
// + lane_tc*4 .. +3): no duplicate embed loads across waves; one coalesced
// 256 B L2 load per wave per k-step.
// Per-thread tile: 16 rows x 4 codes = 64 fp32 accumulators.
// dist = enorm[j] - 2*score  (||x||^2 is a row-constant, order-preserving).
// Tie-break matches numpy argmax(-dist) first-occurrence: codes visited in
// ascending index order with strict <, plus (d==bd && ix<bi) in the final
// cross-thread reduction.
// ---------------------------------------------------------------------------
__global__ __launch_bounds__(256, 2) void dist_argmin_kernel(
    const float* __restrict__ inp,
    const float* __restrict__ embed,
    const float* __restrict__ enorm,
    float* __restrict__ idx_out) {
  __shared__ float As[DIM * TM];  // k-major: As[k*64 + row], 64 KB
  const int t  = threadIdx.x;
  const int r0 = blockIdx.x * TM;

  // Stage A with transpose to k-major.
  // thread: row = t/4 (0..63), kq = t%4; loads float4 (c*4+kq) of its row.
  {
    const int row = t >> 2;
    const int kq  = t & 3;
    const float4* src =
        reinterpret_cast<const float4*>(inp + (size_t)(r0 + row) * DIM);
#pragma unroll
    for (int c = 0; c < 16; ++c) {
      const int k4 = c * 4 + kq;  // float4 index within the row
      const float4 v = src[k4];
      const int k = k4 * 4;
      As[(k + 0) * TM + row] = v.x;
      As[(k + 1) * TM + row] = v.y;
      As[(k + 2) * TM + row] = v.z;
      As[(k + 3) * TM + row] = v.w;
    }
  }
  __syncthreads();

  const int w     = t >> 6;         // wave id 0..3 -> code subgroup
  const int tc    = (t & 15) * 4;   // 0..60: 4 consecutive codes
  const int rg    = (t >> 4) & 3;   // row group 0..3
  const int rbase = rg * 16;        // rows rbase .. rbase+15

  float best_d[16];
  int   best_i[16];
#pragma unroll
  for (int i = 0; i < 16; ++i) { best_d[i] = 3.4e38f; best_i[i] = 0; }

  for (int ct = 0; ct < NE / 256; ++ct) {  // 8 iterations
    const int j0 = ct * 256 + w * 64 + tc;
    float acc[64];
#pragma unroll
    for (int i = 0; i < 64; ++i) acc[i] = 0.f;

    const float* bp = embed + j0;
#pragma unroll 2
    for (int k = 0; k < DIM; ++k) {
      const float4 b = *reinterpret_cast<const float4*>(bp);
      bp += NE;
      const float* arow = As + k * TM + rbase;
      const float4 a0 = *reinterpret_cast<const float4*>(arow);
      const float4 a1 = *reinterpret_cast<const float4*>(arow + 4);
      const float4 a2 = *reinterpret_cast<const float4*>(arow + 8);
      const float4 a3 = *reinterpret_cast<const float4*>(arow + 12);
      const float av[16] = {a0.x, a0.y, a0.z, a0.w, a1.x, a1.y, a1.z, a1.w,
                            a2.x, a2.y, a2.z, a2.w, a3.x, a3.y, a3.z, a3.w};
#pragma unroll
      for (int i = 0; i < 16; ++i) {
        acc[i * 4 + 0] = fmaf(av[i], b.x, acc[i * 4 + 0]);
        acc[i * 4 + 1] = fmaf(av[i], b.y, acc[i * 4 + 1]);
        acc[i * 4 + 2] = fmaf(av[i], b.z, acc[i * 4 + 2]);
        acc[i * 4 + 3] = fmaf(av[i], b.w, acc[i * 4 + 3]);
      }
    }

    const float4 en = *reinterpret_cast<const float4*>(enorm + j0);
    const float enr[4] = {en.x, en.y, en.z, en.w};
#pragma unroll
    for (int i = 0; i < 16; ++i) {
#pragma unroll
      for (int j = 0; j < 4; ++j) {
        const float d = fmaf(-2.f, acc[i * 4 + j], enr[j]);
        if (d < best_d[i]) {  // strict <: first (lowest-index) occurrence wins
          best_d[i] = d;
          best_i[i] = j0 + j;
        }
      }
    }
  }

  // Cross-thread reduction: each row has 64 candidates (16 tc-groups x 4 waves).
  __syncthreads();
  float* red_d = As;                                   // [64][64] floats
  int*   red_i = reinterpret_cast<int*>(As + 64 * 64); // [64][64] ints
  const int col = w * 16 + (t & 15);  // 0..63
#pragma unroll
  for (int i = 0; i < 16; ++i) {
    const int r = rbase + i;
    red_d[r * 64 + col] = best_d[i];
    red_i[r * 64 + col] = best_i[i];
  }
  __syncthreads();
  if (t < TM) {
    float bd = 3.4e38f;
    int   bi = 1 << 30;
    for (int c = 0; c < 64; ++c) {
      const float d  = red_d[t * 64 + c];
      const int   ix = red_i[t * 64 + c];
      if (d < bd || (d == bd && ix < bi)) { bd = d; bi = ix; }
    }
    idx_out[r0 + t] = (float)bi;
  }
}

// ---------------------------------------------------------------------------
// Kernel C: codebook gather + straight-through output + per-block diff partial
// ---------------------------------------------------------------------------
__global__ __launch_bounds__(256) void gather_diff_kernel(
    const float* __restrict__ inp,
    const float* __restrict__ embT,
    const float* __restrict__ idxf,
    float* __restrict__ q_out,
    float* __restrict__ partials) {
  __shared__ float wsum[4];
  const int t    = threadIdx.x;
  const int row  = blockIdx.x * GATHER_ROWS_PER_BLOCK + (t >> 6);
  const int lane = t & 63;
  const int d    = lane * 4;

  const int idx = (int)idxf[row];  // exact: 0..2047
  const float4 x = *reinterpret_cast<const float4*>(inp + (size_t)row * DIM + d);
  const float4 e = *reinterpret_cast<const float4*>(embT + (size_t)idx * DIM + d);

  float4 dq, q;
  dq.x = e.x - x.x; dq.y = e.y - x.y; dq.z = e.z - x.z; dq.w = e.w - x.w;
  // reference: quantize = input + stop_gradient(quantize - input)
  q.x = x.x + dq.x; q.y = x.y + dq.y; q.z = x.z + dq.z; q.w = x.w + dq.w;
  *reinterpret_cast<float4*>(q_out + (size_t)row * DIM + d) = q;

  float s = dq.x * dq.x + dq.y * dq.y + dq.z * dq.z + dq.w * dq.w;
#pragma unroll
  for (int o = 32; o > 0; o >>= 1) s += __shfl_down(s, o, 64);
  if (lane == 0) wsum[t >> 6] = s;
  __syncthreads();
  if (t == 0) partials[blockIdx.x] = wsum[0] + wsum[1] + wsum[2] + wsum[3];
}

// ---------------------------------------------------------------------------
// Kernel D: final diff reduction (deterministic, no atomics)
// ---------------------------------------------------------------------------
__global__ __launch_bounds__(256) void final_diff_kernel(
    const float* __restrict__ partials, float* __restrict__ diff_out) {
  __shared__ float wsum[4];
  const int t = threadIdx.x;
  float s = 0.f;
  for (int k = 0; k < NBLK_C / 256; ++k) s += partials[t + k * 256];
#pragma unroll
  for (int o = 32; o > 0; o >>= 1) s += __shfl_down(s, o, 64);
  if ((t & 63) == 0) wsum[t >> 6] = s;
  __syncthreads();
  if (t == 0) {
    const float total = wsum[0] + wsum[1] + wsum[2] + wsum[3];
    diff_out[0] = total * (1.0f / (float)((size_t)NROWS * DIM));
  }
}

// ---------------------------------------------------------------------------
extern "C" void kernel_launch(void* const* d_in, const int* in_sizes, int n_in,
                              void* d_out, int out_size, void* d_ws,
                              size_t ws_size, hipStream_t stream) {
  (void)in_sizes; (void)n_in; (void)out_size; (void)ws_size;
  const float* inp   = (const float*)d_in[0];
  const float* embed = (const float*)d_in[1];

  float* out      = (float*)d_out;
  float* q_out    = out;                       // 33554432 floats
  float* diff_out = out + (size_t)NROWS * DIM; // 1 float
  float* idx_out  = diff_out + 1;              // 131072 floats

  float* ws       = (float*)d_ws;
  float* embT     = ws;                 // 524288 floats (2 MB)
  float* enorm    = ws + (size_t)NE * DIM;       // 2048 floats
  float* partials = enorm + NE;                  // 32768 floats

  enorm_kernel<<<NE / 256, 256, 0, stream>>>(embed, enorm);
  transpose_kernel<<<dim3(NE / 32, DIM / 32), dim3(32, 8), 0, stream>>>(embed, embT);
  dist_argmin_kernel<<<NBLK_B, 256, 0, stream>>>(inp, embed, enorm, idx_out);
  gather_diff_kernel<<<NBLK_C, 256, 0, stream>>>(inp, embT, idx_out, q_out, partials);
  final_diff_kernel<<<1, 256, 0, stream>>>(partials, diff_out);
}

// Round 2
// 1520.786 us; speedup vs baseline: 1.3612x; 1.3612x over previous
//
#include <hip/hip_runtime.h>
#include <cstdint>

// Problem: input [32,64,64,256] fp32 = 131072 rows x 256; embed [256,2048] fp32.
// d_out (fp32): quantize[33554432] | diff[1] | embed_ind_as_float[131072]
//
// Strategy: split-bf16 MFMA distance GEMM (xh+xl)(eh+el) with 3 MFMA terms,
// per-row top-2 candidate tracking, then exact fp32 refine of the 2 candidates
// fused with the gather/straight-through/diff epilogue.

#define NROWS   131072
#define DIM     256
#define NE      2048
#define BM      64                    // rows per pass1 block
#define NBLK_P1 (NROWS / BM)          // 2048
#define GROWS   4
#define NBLK_RG (NROWS / GROWS)       // 32768

typedef __attribute__((ext_vector_type(8))) short bf16x8;
typedef __attribute__((ext_vector_type(4))) float f32x4;

__device__ __forceinline__ ushort bf16_rne(float v) {
  uint u = __float_as_uint(v);
  return (ushort)((u + 0x7FFFu + ((u >> 16) & 1u)) >> 16);
}
__device__ __forceinline__ void split_hi_lo(float v, ushort& h, ushort& l) {
  h = bf16_rne(v);
  const float hf = __uint_as_float(((uint)h) << 16);
  l = bf16_rne(v - hf);
}

// ---------------------------------------------------------------------------
// enorm[j] = sum_d embed[d][j]^2   (fp32, matches round-1 validated math)
// ---------------------------------------------------------------------------
__global__ __launch_bounds__(256) void enorm_kernel(
    const float* __restrict__ embed, float* __restrict__ enorm) {
  const int j = blockIdx.x * 256 + threadIdx.x;
  float s = 0.f;
#pragma unroll 8
  for (int d = 0; d < DIM; ++d) {
    const float v = embed[(size_t)d * NE + j];
    s = fmaf(v, v, s);
  }
  enorm[j] = s;
}

// ---------------------------------------------------------------------------
// embT[j][d] = embed[d][j]
// ---------------------------------------------------------------------------
__global__ __launch_bounds__(256) void transpose_kernel(
    const float* __restrict__ embed, float* __restrict__ embT) {
  __shared__ float tile[32][33];
  const int tx = threadIdx.x;  // 0..31
  const int ty = threadIdx.y;  // 0..7
  const int j0 = blockIdx.x * 32;
  const int d0 = blockIdx.y * 32;
#pragma unroll
  for (int i = 0; i < 4; ++i) {
    const int dd = ty + i * 8;
    tile[dd][tx] = embed[(size_t)(d0 + dd) * NE + j0 + tx];
  }
  __syncthreads();
#pragma unroll
  for (int i = 0; i < 4; ++i) {
    const int jj = ty + i * 8;
    embT[(size_t)(j0 + jj) * DIM + d0 + tx] = tile[tx][jj];
  }
}

// ---------------------------------------------------------------------------
// Pack embed into bf16 hi/lo in MFMA-B-fragment order:
// ebh4[(ct*8+ks)*64 + lane] = 8 bf16 of code ct*16+(lane&15),
//                             k = ks*32 + (lane>>4)*8 .. +7
// so the pass1 wave's B-frag load is one fully-coalesced 1 KB b128 read.
// ---------------------------------------------------------------------------
__global__ __launch_bounds__(256) void pack_embed_kernel(
    const float* __restrict__ embT, uint4* __restrict__ ebh4,
    uint4* __restrict__ ebl4) {
  const int g    = blockIdx.x * 256 + threadIdx.x;  // 0..65535
  const int ct   = g >> 9;
  const int r    = g & 511;
  const int ks   = r >> 6;
  const int lane = r & 63;
  const int code = ct * 16 + (lane & 15);
  const int k0   = ks * 32 + (lane >> 4) * 8;
  const float* src = embT + (size_t)code * DIM + k0;
  const float4 a = *(const float4*)(src);
  const float4 b = *(const float4*)(src + 4);
  ushort h[8], l[8];
  split_hi_lo(a.x, h[0], l[0]); split_hi_lo(a.y, h[1], l[1]);
  split_hi_lo(a.z, h[2], l[2]); split_hi_lo(a.w, h[3], l[3]);
  split_hi_lo(b.x, h[4], l[4]); split_hi_lo(b.y, h[5], l[5]);
  split_hi_lo(b.z, h[6], l[6]); split_hi_lo(b.w, h[7], l[7]);
  uint4 hv, lv;
  hv.x = (uint)h[0] | ((uint)h[1] << 16); hv.y = (uint)h[2] | ((uint)h[3] << 16);
  hv.z = (uint)h[4] | ((uint)h[5] << 16); hv.w = (uint)h[6] | ((uint)h[7] << 16);
  lv.x = (uint)l[0] | ((uint)l[1] << 16); lv.y = (uint)l[2] | ((uint)l[3] << 16);
  lv.z = (uint)l[4] | ((uint)l[5] << 16); lv.w = (uint)l[6] | ((uint)l[7] << 16);
  ebh4[g] = hv;
  ebl4[g] = lv;
}

// ---------------------------------------------------------------------------
// Pass 1: split-bf16 MFMA distance GEMM + per-row top-2.
// Block = 256 thr (4 waves), 64 rows. A (hi/lo) staged in LDS in A-frag order.
// Wave w owns codes [w*512, w*512+512), in 8 chunks of 64 (4 n-tiles).
// Per k-step: 8 ds_read_b128 (A) + 8 global b128 (B, L2-resident) + 48 MFMA.
// dist = enorm[j] - 2*score (row-constant ||x||^2 dropped, order-preserving).
// Top-2 per (lane,row) -> LDS merge -> exact block top-2 -> packed u16 pair.
// ---------------------------------------------------------------------------
__global__ __launch_bounds__(256, 2) void pass1_kernel(
    const float* __restrict__ inp, const uint4* __restrict__ ebh4,
    const uint4* __restrict__ ebl4, const float* __restrict__ enorm,
    uint* __restrict__ cand) {
  __shared__ __align__(16) uint smem[16384];  // 64 KB
  ushort* AhL = (ushort*)smem;                // 32 KB
  ushort* AlL = AhL + 16384;                  // 32 KB
  const int t  = threadIdx.x;
  const int r0 = blockIdx.x * BM;

  // Stage A: fp32 -> bf16 hi/lo, A-frag layout:
  // index = ((rt*8+ks)*64 + kg*16 + m)*8 + j  for element (row=rt*16+m, k=ks*32+kg*8+j)
  {
    const int row = t >> 2, kq = t & 3;
    const int art = row >> 4, m = row & 15;
    const float4* src = (const float4*)(inp + (size_t)(r0 + row) * DIM);
#pragma unroll
    for (int c = 0; c < 16; ++c) {
      const int k4 = c * 4 + kq;
      const float4 v = src[k4];
      const int k = k4 * 4;
      const int aks = k >> 5, akg = (k >> 3) & 3, j = k & 7;
      const int idx = ((art * 8 + aks) * 64 + akg * 16 + m) * 8 + j;
      ushort h0, h1, h2, h3, l0, l1, l2, l3;
      split_hi_lo(v.x, h0, l0); split_hi_lo(v.y, h1, l1);
      split_hi_lo(v.z, h2, l2); split_hi_lo(v.w, h3, l3);
      ushort4 hv; hv.x = h0; hv.y = h1; hv.z = h2; hv.w = h3;
      ushort4 lv; lv.x = l0; lv.y = l1; lv.z = l2; lv.w = l3;
      *(ushort4*)(AhL + idx) = hv;
      *(ushort4*)(AlL + idx) = lv;
    }
  }
  __syncthreads();

  const int wv = t >> 6, lane = t & 63, col = lane & 15, kg = lane >> 4;
  float td1[16], td2[16];
  uint  ti[16];  // low16 = best idx, high16 = second idx
#pragma unroll
  for (int i = 0; i < 16; ++i) { td1[i] = 3.4e38f; td2[i] = 3.4e38f; ti[i] = 0u; }

  for (int ch = 0; ch < 8; ++ch) {
    const int cb  = wv * 512 + ch * 64;
    const int ctb = cb >> 4;
    f32x4 acc[4][4];
#pragma unroll
    for (int rt = 0; rt < 4; ++rt)
#pragma unroll
      for (int nt = 0; nt < 4; ++nt) acc[rt][nt] = (f32x4){0.f, 0.f, 0.f, 0.f};

#pragma unroll
    for (int ks = 0; ks < 8; ++ks) {
      bf16x8 ah[4], al[4], bh[4], bl[4];
#pragma unroll
      for (int nt = 0; nt < 4; ++nt) {
        const int bi = (ctb + nt) * 512 + ks * 64 + lane;
        bh[nt] = *(const bf16x8*)(ebh4 + bi);
        bl[nt] = *(const bf16x8*)(ebl4 + bi);
      }
#pragma unroll
      for (int rt = 0; rt < 4; ++rt) {
        const int ai = ((rt * 8 + ks) * 64 + lane) * 8;
        ah[rt] = *(const bf16x8*)(AhL + ai);
        al[rt] = *(const bf16x8*)(AlL + ai);
      }
#pragma unroll
      for (int rt = 0; rt < 4; ++rt)
#pragma unroll
        for (int nt = 0; nt < 4; ++nt) {
          acc[rt][nt] = __builtin_amdgcn_mfma_f32_16x16x32_bf16(
              ah[rt], bh[nt], acc[rt][nt], 0, 0, 0);
          acc[rt][nt] = __builtin_amdgcn_mfma_f32_16x16x32_bf16(
              ah[rt], bl[nt], acc[rt][nt], 0, 0, 0);
          acc[rt][nt] = __builtin_amdgcn_mfma_f32_16x16x32_bf16(
              al[rt], bh[nt], acc[rt][nt], 0, 0, 0);
        }
    }

    // epilogue: dist + top-2 update (codes ascend -> first-occurrence ties)
#pragma unroll
    for (int nt = 0; nt < 4; ++nt) {
      const uint code = (uint)(cb + nt * 16 + col);
      const float en  = enorm[code];
#pragma unroll
      for (int rt = 0; rt < 4; ++rt)
#pragma unroll
        for (int reg = 0; reg < 4; ++reg) {
          const float dd = fmaf(-2.f, acc[rt][nt][reg], en);
          const int ri = rt * 4 + reg;
          if (dd < td1[ri]) {
            td2[ri] = td1[ri];
            ti[ri]  = (ti[ri] << 16) | code;
            td1[ri] = dd;
          } else if (dd < td2[ri]) {
            td2[ri] = dd;
            ti[ri]  = (ti[ri] & 0xFFFFu) | (code << 16);
          }
        }
    }
  }

  // Cross-wave merge: per row, 64 slots x 2 candidates in LDS (reuses A area).
  __syncthreads();
  float* rdF = (float*)smem;
  uint*  rdI = smem;
#pragma unroll
  for (int rt = 0; rt < 4; ++rt)
#pragma unroll
    for (int reg = 0; reg < 4; ++reg) {
      const int ri   = rt * 4 + reg;
      const int row  = rt * 16 + kg * 4 + reg;
      const int slot = wv * 16 + col;
      const int base = (row * 64 + slot) * 4;
      rdF[base + 0] = td1[ri];
      rdI[base + 1] = ti[ri] & 0xFFFFu;
      rdF[base + 2] = td2[ri];
      rdI[base + 3] = ti[ri] >> 16;
    }
  __syncthreads();
  if (t < BM) {
    float D1 = 3.4e38f, D2 = 3.4e38f;
    uint  I1 = 0xFFFFu, I2 = 0xFFFFu;
    for (int s = 0; s < 64; ++s) {
      const int base = (t * 64 + s) * 4;
#pragma unroll
      for (int c = 0; c < 2; ++c) {
        const float d = rdF[base + c * 2];
        const uint  i = rdI[base + c * 2 + 1];
        if (d < D1 || (d == D1 && i < I1)) {
          D2 = D1; I2 = I1; D1 = d; I1 = i;
        } else if (d < D2 || (d == D2 && i < I2)) {
          D2 = d; I2 = i;
        }
      }
    }
    cand[r0 + t] = I1 | (I2 << 16);
  }
}

// ---------------------------------------------------------------------------
// Refine + gather + diff: exact fp32 distances for the 2 candidates, pick
// winner (first-occurrence tie-break), codebook lookup, straight-through
// output q = x + (e - x), per-block diff partial. Candidates are read from
// the idx_out region (bit-packed u32) and overwritten with the float index.
// ---------------------------------------------------------------------------
__global__ __launch_bounds__(256) void refine_gather_kernel(
    const float* __restrict__ inp, const float* __restrict__ embT,
    const float* __restrict__ enorm, float* __restrict__ q_out,
    float* __restrict__ idx_out, float* __restrict__ partials) {
  __shared__ float wsum[4];
  const int t    = threadIdx.x;
  const int row  = blockIdx.x * GROWS + (t >> 6);
  const int lane = t & 63;
  const int d4   = lane * 4;

  const uint u = ((const uint*)idx_out)[row];
  const int i1 = (int)(u & 0xFFFFu);
  const int i2 = (int)(u >> 16);

  const float4 x  = *(const float4*)(inp  + (size_t)row * DIM + d4);
  const float4 e1 = *(const float4*)(embT + (size_t)i1 * DIM + d4);
  const float4 e2 = *(const float4*)(embT + (size_t)i2 * DIM + d4);

  float s1 = x.x * e1.x + x.y * e1.y + x.z * e1.z + x.w * e1.w;
  float s2 = x.x * e2.x + x.y * e2.y + x.z * e2.z + x.w * e2.w;
#pragma unroll
  for (int o = 32; o > 0; o >>= 1) {
    s1 += __shfl_xor(s1, o, 64);
    s2 += __shfl_xor(s2, o, 64);
  }
  const float dd1 = fmaf(-2.f, s1, enorm[i1]);
  const float dd2 = fmaf(-2.f, s2, enorm[i2]);
  const bool take2 = (dd2 < dd1) || (dd2 == dd1 && i2 < i1);
  const float4 e = take2 ? e2 : e1;
  const int  win = take2 ? i2 : i1;

  float4 dq, q;
  dq.x = e.x - x.x; dq.y = e.y - x.y; dq.z = e.z - x.z; dq.w = e.w - x.w;
  q.x = x.x + dq.x; q.y = x.y + dq.y; q.z = x.z + dq.z; q.w = x.w + dq.w;
  *(float4*)(q_out + (size_t)row * DIM + d4) = q;
  if (lane == 0) idx_out[row] = (float)win;

  float s = dq.x * dq.x + dq.y * dq.y + dq.z * dq.z + dq.w * dq.w;
#pragma unroll
  for (int o = 32; o > 0; o >>= 1) s += __shfl_down(s, o, 64);
  if (lane == 0) wsum[t >> 6] = s;
  __syncthreads();
  if (t == 0) partials[blockIdx.x] = wsum[0] + wsum[1] + wsum[2] + wsum[3];
}

// ---------------------------------------------------------------------------
__global__ __launch_bounds__(256) void final_diff_kernel(
    const float* __restrict__ partials, float* __restrict__ diff_out) {
  __shared__ float wsum[4];
  const int t = threadIdx.x;
  float s = 0.f;
  for (int k = 0; k < NBLK_RG / 256; ++k) s += partials[t + k * 256];
#pragma unroll
  for (int o = 32; o > 0; o >>= 1) s += __shfl_down(s, o, 64);
  if ((t & 63) == 0) wsum[t >> 6] = s;
  __syncthreads();
  if (t == 0) {
    const float total = wsum[0] + wsum[1] + wsum[2] + wsum[3];
    diff_out[0] = total * (1.0f / (float)((size_t)NROWS * DIM));
  }
}

// ---------------------------------------------------------------------------
extern "C" void kernel_launch(void* const* d_in, const int* in_sizes, int n_in,
                              void* d_out, int out_size, void* d_ws,
                              size_t ws_size, hipStream_t stream) {
  (void)in_sizes; (void)n_in; (void)out_size; (void)ws_size;
  const float* inp   = (const float*)d_in[0];
  const float* embed = (const float*)d_in[1];

  float* out      = (float*)d_out;
  float* q_out    = out;                        // 33554432 floats
  float* diff_out = out + (size_t)NROWS * DIM;  // 1 float
  float* idx_out  = diff_out + 1;               // 131072 floats (cand scratch)

  float* ws       = (float*)d_ws;
  float* embT     = ws;                          // 524288 floats (2 MB)
  float* enorm    = ws + (size_t)NE * DIM;       // 2048 floats
  float* partials = enorm + NE;                  // 32768 floats
  float* ebh      = partials + NBLK_RG;          // 262144 floats (1 MB as bf16)
  float* ebl      = ebh + (size_t)NE * DIM / 2;  // 262144 floats (1 MB as bf16)
  uint4* ebh4     = (uint4*)ebh;
  uint4* ebl4     = (uint4*)ebl;

  enorm_kernel<<<NE / 256, 256, 0, stream>>>(embed, enorm);
  transpose_kernel<<<dim3(NE / 32, DIM / 32), dim3(32, 8), 0, stream>>>(embed, embT);
  pack_embed_kernel<<<(NE / 16) * 8 * 64 / 256, 256, 0, stream>>>(embT, ebh4, ebl4);
  pass1_kernel<<<NBLK_P1, 256, 0, stream>>>(inp, ebh4, ebl4, enorm,
                                            (uint*)idx_out);
  refine_gather_kernel<<<NBLK_RG, 256, 0, stream>>>(inp, embT, enorm, q_out,
                                                    idx_out, partials);
  final_diff_kernel<<<1, 256, 0, stream>>>(partials, diff_out);
}